// Round 1
// baseline (17119.069 us; speedup 1.0000x reference)
//
#include <hip/hip_runtime.h>
#include <cstdint>
#include <cstddef>

#define TT 128   // T
#define NBATCH 16
#define HH 1024
#define G4 4096  // 4*H

typedef __attribute__((ext_vector_type(8))) short bf16x8;
typedef __attribute__((ext_vector_type(4))) float f32x4;

// ---------------- embedding gather ----------------
__global__ __launch_bounds__(256) void embed_kernel(const int* __restrict__ y,
    const float* __restrict__ embed, float* __restrict__ emb) {
  int idx = blockIdx.x * 256 + threadIdx.x;   // float4 index over [2048][128]
  int n = idx >> 7, c = idx & 127;
  int tok = y[n];
  reinterpret_cast<float4*>(emb)[idx] =
      reinterpret_cast<const float4*>(embed)[(size_t)tok * 128 + c];
}

// ---------------- split-bf16 helpers (truncation split: x = hi + lo + O(2^-14 x)) ----
__device__ __forceinline__ unsigned pkhi(float x, float y) {
  // pack bf16(x) in low 16, bf16(y) in high 16 (truncation)
  return (__float_as_uint(x) >> 16) | (__float_as_uint(y) & 0xFFFF0000u);
}
__device__ __forceinline__ float bfres(float x) {
  return x - __uint_as_float(__float_as_uint(x) & 0xFFFF0000u);
}

// ---------------- MFMA GEMM: C[M,N] = A[M,K]*W[N,K]^T + b1 (+b2), opt tanh --------
// 128x128 tile, BK=32, 4 waves in 2x2, wave tile 64x64 = 4x4 frags of 16x16x32.
// fp32 inputs are split on the fly into (hi,lo) bf16 tiles in LDS; each frag pair
// contributes hi*hi + hi*lo + lo*hi into the fp32 accumulator (lo*lo ~2^-16, dropped).
// LDS rows padded to 40 shorts (80 B): fragment reads are 2-way (free) per m136.
__global__ __launch_bounds__(256, 2) void gemm_mfma(
    const float* __restrict__ A, const float* __restrict__ W,
    const float* __restrict__ b1, const float* __restrict__ b2,
    float* __restrict__ C, int M, int N, int K, int act) {
  __shared__ short Ah[128][40];
  __shared__ short Al[128][40];
  __shared__ short Wh[128][40];
  __shared__ short Wl[128][40];

  const int tid = threadIdx.x;
  const int m0 = blockIdx.y * 128, n0 = blockIdx.x * 128;
  const int sr = tid >> 1;          // staging row 0..127
  const int kh = tid & 1;           // staging k-half (16 floats each)
  const int lane = tid & 63;
  const int wv = tid >> 6;          // wave 0..3
  const int wr = wv >> 1, wc = wv & 1;
  const int lr = lane & 15;         // frag row/col
  const int kg = lane >> 4;         // k-group 0..3 (8 elems each)

  const float* Ap = A + (size_t)(m0 + sr) * K + kh * 16;
  const float* Wp = W + (size_t)(n0 + sr) * K + kh * 16;

  f32x4 zero = {0.f, 0.f, 0.f, 0.f};
  f32x4 acc[4][4];
#pragma unroll
  for (int m = 0; m < 4; ++m)
#pragma unroll
    for (int n = 0; n < 4; ++n) acc[m][n] = zero;

  // prologue: stage k-tile 0 into registers
  float4 qa[4], qw[4];
#pragma unroll
  for (int i = 0; i < 4; ++i) {
    qa[i] = *reinterpret_cast<const float4*>(Ap + i * 4);
    qw[i] = *reinterpret_cast<const float4*>(Wp + i * 4);
  }

  for (int k0 = 0; k0 < K; k0 += 32) {
    // ---- convert staged regs -> hi/lo bf16 LDS tiles ----
    {
      unsigned ha[8], la[8], hw[8], lw[8];
#pragma unroll
      for (int i = 0; i < 4; ++i) {
        ha[2 * i]     = pkhi(qa[i].x, qa[i].y);
        ha[2 * i + 1] = pkhi(qa[i].z, qa[i].w);
        la[2 * i]     = pkhi(bfres(qa[i].x), bfres(qa[i].y));
        la[2 * i + 1] = pkhi(bfres(qa[i].z), bfres(qa[i].w));
        hw[2 * i]     = pkhi(qw[i].x, qw[i].y);
        hw[2 * i + 1] = pkhi(qw[i].z, qw[i].w);
        lw[2 * i]     = pkhi(bfres(qw[i].x), bfres(qw[i].y));
        lw[2 * i + 1] = pkhi(bfres(qw[i].z), bfres(qw[i].w));
      }
      *reinterpret_cast<uint4*>(&Ah[sr][kh * 16])     = make_uint4(ha[0], ha[1], ha[2], ha[3]);
      *reinterpret_cast<uint4*>(&Ah[sr][kh * 16 + 8]) = make_uint4(ha[4], ha[5], ha[6], ha[7]);
      *reinterpret_cast<uint4*>(&Al[sr][kh * 16])     = make_uint4(la[0], la[1], la[2], la[3]);
      *reinterpret_cast<uint4*>(&Al[sr][kh * 16 + 8]) = make_uint4(la[4], la[5], la[6], la[7]);
      *reinterpret_cast<uint4*>(&Wh[sr][kh * 16])     = make_uint4(hw[0], hw[1], hw[2], hw[3]);
      *reinterpret_cast<uint4*>(&Wh[sr][kh * 16 + 8]) = make_uint4(hw[4], hw[5], hw[6], hw[7]);
      *reinterpret_cast<uint4*>(&Wl[sr][kh * 16])     = make_uint4(lw[0], lw[1], lw[2], lw[3]);
      *reinterpret_cast<uint4*>(&Wl[sr][kh * 16 + 8]) = make_uint4(lw[4], lw[5], lw[6], lw[7]);
    }
    __syncthreads();

    // ---- issue global loads for next k-tile (latency hides under MFMA) ----
    if (k0 + 32 < K) {
#pragma unroll
      for (int i = 0; i < 4; ++i) {
        qa[i] = *reinterpret_cast<const float4*>(Ap + k0 + 32 + i * 4);
        qw[i] = *reinterpret_cast<const float4*>(Wp + k0 + 32 + i * 4);
      }
    }

    // ---- fragment loads (lane lr = row, kg*8 = k offset; 80 B stride -> 2-way free) ----
    bf16x8 fah[4], fal[4], fbh[4], fbl[4];
#pragma unroll
    for (int m = 0; m < 4; ++m) {
      fah[m] = *reinterpret_cast<const bf16x8*>(&Ah[wr * 64 + m * 16 + lr][kg * 8]);
      fal[m] = *reinterpret_cast<const bf16x8*>(&Al[wr * 64 + m * 16 + lr][kg * 8]);
      fbh[m] = *reinterpret_cast<const bf16x8*>(&Wh[wc * 64 + m * 16 + lr][kg * 8]);
      fbl[m] = *reinterpret_cast<const bf16x8*>(&Wl[wc * 64 + m * 16 + lr][kg * 8]);
    }

    // ---- 48 MFMA, combo-outer so each acc is revisited every 16 (no dep stalls) ----
#pragma unroll
    for (int m = 0; m < 4; ++m)
#pragma unroll
      for (int n = 0; n < 4; ++n)
        acc[m][n] = __builtin_amdgcn_mfma_f32_16x16x32_bf16(fah[m], fbh[n], acc[m][n], 0, 0, 0);
#pragma unroll
    for (int m = 0; m < 4; ++m)
#pragma unroll
      for (int n = 0; n < 4; ++n)
        acc[m][n] = __builtin_amdgcn_mfma_f32_16x16x32_bf16(fah[m], fbl[n], acc[m][n], 0, 0, 0);
#pragma unroll
    for (int m = 0; m < 4; ++m)
#pragma unroll
      for (int n = 0; n < 4; ++n)
        acc[m][n] = __builtin_amdgcn_mfma_f32_16x16x32_bf16(fal[m], fbh[n], acc[m][n], 0, 0, 0);
    __syncthreads();   // protect next iteration's LDS writes from this iter's reads
  }

  // ---- epilogue: C[row = (lane>>4)*4 + r][col = lane&15] (m89-verified layout) ----
#pragma unroll
  for (int m = 0; m < 4; ++m) {
    int grow = m0 + wr * 64 + m * 16 + kg * 4;
#pragma unroll
    for (int n = 0; n < 4; ++n) {
      int gcol = n0 + wc * 64 + n * 16 + lr;
      float bias = b1[gcol] + (b2 ? b2[gcol] : 0.f);
#pragma unroll
      for (int rr = 0; rr < 4; ++rr) {
        float v = acc[m][n][rr] + bias;
        if (act) v = tanhf(v);
        C[(size_t)(grow + rr) * N + gcol] = v;
      }
    }
  }
}

// ---------------- grid barrier (spin, agent scope) ----------------
__device__ __forceinline__ void grid_barrier(unsigned* bar, unsigned nblocks) {
  __threadfence();
  __syncthreads();
  if (threadIdx.x == 0) {
    unsigned g = __hip_atomic_load(&bar[1], __ATOMIC_ACQUIRE, __HIP_MEMORY_SCOPE_AGENT);
    unsigned a = __hip_atomic_fetch_add(&bar[0], 1u, __ATOMIC_ACQ_REL, __HIP_MEMORY_SCOPE_AGENT);
    if (a == nblocks - 1) {
      __hip_atomic_store(&bar[0], 0u, __ATOMIC_RELAXED, __HIP_MEMORY_SCOPE_AGENT);
      __hip_atomic_fetch_add(&bar[1], 1u, __ATOMIC_RELEASE, __HIP_MEMORY_SCOPE_AGENT);
    } else {
      while (__hip_atomic_load(&bar[1], __ATOMIC_ACQUIRE, __HIP_MEMORY_SCOPE_AGENT) == g) {
        __builtin_amdgcn_s_sleep(2);
      }
    }
  }
  __syncthreads();
  __threadfence();
}

// ---------------- LSTM layer: persistent, 256 blocks, W_hh in registers ----------
__global__ __launch_bounds__(256) void lstm_kernel(
    const float* __restrict__ xg,    // [B*T, 4H], includes b_ih + b_hh
    const float* __restrict__ W_hh,  // [4H, H]
    const float* __restrict__ h0,    // [B,H] (layer slice)
    const float* __restrict__ c0,    // [B,H]
    float* __restrict__ hbuf0,       // [B,H] state buffer (even steps read)
    float* __restrict__ hbuf1,       // [B,H] state buffer (odd steps read)
    float* __restrict__ hs,          // [B*T, H] layer output
    unsigned* __restrict__ bar) {
  __shared__ float4 lds_h[16 * 256];                       // 64 KB: h[b][256 f4]
  float* lds_g = reinterpret_cast<float*>(lds_h);          // aliased gates [16][17]

  const int tid = threadIdx.x;
  const int bid = blockIdx.x;
  const int r = tid >> 4;          // 0..15
  const int ks = tid & 15;         // 0..15
  const int gate = r >> 2, jj = r & 3;
  const int grow = gate * HH + bid * 4 + jj;   // row in W_hh / column in xg

  // persistent W_hh fragment: 64 floats, k = ks*4 + 64*m + e
  float4 wreg[16];
#pragma unroll
  for (int m = 0; m < 16; ++m)
    wreg[m] = *reinterpret_cast<const float4*>(W_hh + (size_t)grow * HH + ks * 4 + 64 * m);

  // init c (held by consumer threads) and our slice of the step-0 read buffer
  float c_reg = 0.f;
  if (tid < 64) {
    int b = tid & 15, jl = tid >> 4;
    int j = bid * 4 + jl;
    c_reg = c0[b * HH + j];
    hbuf0[b * HH + j] = h0[b * HH + j];
  }
  grid_barrier(bar, gridDim.x);

  float* cur = hbuf0;
  float* nxt = hbuf1;
  for (int t = 0; t < TT; ++t) {
    // prefetch this thread's xg value (b = ks)
    float xgv = xg[(size_t)(ks * TT + t) * G4 + grow];
    // stage h -> LDS (read buffer)
    const float4* hg4 = reinterpret_cast<const float4*>(cur);
#pragma unroll
    for (int i = 0; i < 16; ++i) {
      int idx = i * 256 + tid;         // 0..4095
      lds_h[idx] = hg4[idx];
    }
    __syncthreads();
    // partial dots for all 16 batches over this thread's K slice
    float acc[16];
#pragma unroll
    for (int b = 0; b < 16; ++b) {
      float fa = 0.f;
#pragma unroll
      for (int m = 0; m < 16; ++m) {
        float4 hv = lds_h[b * 256 + m * 16 + ks];
        fa += wreg[m].x * hv.x + wreg[m].y * hv.y + wreg[m].z * hv.z + wreg[m].w * hv.w;
      }
      acc[b] = fa;
    }
    // butterfly reduce across the 16 ks lanes (lane = (r&3)*16 + ks; masks flip ks only)
#pragma unroll
    for (int b = 0; b < 16; ++b) {
      float v = acc[b];
      v += __shfl_xor(v, 1);
      v += __shfl_xor(v, 2);
      v += __shfl_xor(v, 4);
      v += __shfl_xor(v, 8);
      acc[b] = v;
    }
    // this thread publishes gate value for b == ks
    float gv = acc[0];
#pragma unroll
    for (int b = 1; b < 16; ++b) if (ks == b) gv = acc[b];
    gv += xgv;
    __syncthreads();                // all lds_h reads done before aliasing as lds_g
    lds_g[r * 17 + ks] = gv;
    __syncthreads();
    if (tid < 64) {
      int b = tid & 15, jl = tid >> 4;
      float gi = lds_g[(0 * 4 + jl) * 17 + b];
      float gf = lds_g[(1 * 4 + jl) * 17 + b];
      float gg = lds_g[(2 * 4 + jl) * 17 + b];
      float go = lds_g[(3 * 4 + jl) * 17 + b];
      float si = 1.f / (1.f + expf(-gi));
      float sf = 1.f / (1.f + expf(-gf));
      float so = 1.f / (1.f + expf(-go));
      c_reg = sf * c_reg + si * tanhf(gg);
      float hv = so * tanhf(c_reg);
      int j = bid * 4 + jl;
      nxt[b * HH + j] = hv;                      // write buffer (no race with readers of cur)
      hs[(size_t)(b * TT + t) * HH + j] = hv;
    }
    grid_barrier(bar, gridDim.x);
    float* tmp = cur; cur = nxt; nxt = tmp;
  }
}

// ---------------- attention + concat: per (b,t) block ----------------
__global__ __launch_bounds__(256) void attn_kernel(
    const float* __restrict__ hs1, const float* __restrict__ enc,
    const int* __restrict__ mask, float* __restrict__ cat) {
  __shared__ float4 q4[256];
  __shared__ float sc[128];
  __shared__ float red[8];
  const int tid = threadIdx.x;
  const int n = blockIdx.x;          // b*T + t
  const int b = n >> 7;

  float4 qv = reinterpret_cast<const float4*>(hs1)[(size_t)n * 256 + tid];
  q4[tid] = qv;
  reinterpret_cast<float4*>(cat)[(size_t)n * 512 + tid] = qv;   // cat first half
  __syncthreads();

  // scores: 2 threads per s (k-split halves)
  const int s = tid >> 1, half = tid & 1;
  const float4* e4 = reinterpret_cast<const float4*>(enc) + ((size_t)(b * 128 + s)) * 256 + half * 128;
  const float4* qq = q4 + half * 128;
  float p = 0.f;
#pragma unroll 8
  for (int k = 0; k < 128; ++k) {
    float4 ev = e4[k]; float4 qk = qq[k];
    p += ev.x * qk.x + ev.y * qk.y + ev.z * qk.z + ev.w * qk.w;
  }
  p += __shfl_xor(p, 1);
  if (half == 0) sc[s] = (mask[b * 128 + s] != 0) ? p : -1.0e9f;
  __syncthreads();

  // softmax over 128 scores
  const int lane = tid & 63;
  float v = (tid < 128) ? sc[tid] : -3.4e38f;
#pragma unroll
  for (int off = 32; off; off >>= 1) v = fmaxf(v, __shfl_xor(v, off));
  if (tid < 128 && lane == 0) red[tid >> 6] = v;
  __syncthreads();
  float mx = fmaxf(red[0], red[1]);
  float e = (tid < 128) ? expf(sc[tid] - mx) : 0.f;
  float sum = e;
#pragma unroll
  for (int off = 32; off; off >>= 1) sum += __shfl_xor(sum, off);
  if (lane == 0) red[4 + (tid >> 6)] = sum;
  __syncthreads();
  float tot = red[4] + red[5] + red[6] + red[7];
  if (tid < 128) sc[tid] = e / tot;
  __syncthreads();

  // ctx: each thread owns 4 h channels
  float4 accv = {0.f, 0.f, 0.f, 0.f};
  const float4* eb = reinterpret_cast<const float4*>(enc) + (size_t)b * 128 * 256;
#pragma unroll 4
  for (int ss = 0; ss < 128; ++ss) {
    float a = sc[ss];
    float4 ev = eb[(size_t)ss * 256 + tid];
    accv.x += a * ev.x; accv.y += a * ev.y; accv.z += a * ev.z; accv.w += a * ev.w;
  }
  reinterpret_cast<float4*>(cat)[(size_t)n * 512 + 256 + tid] = accv;
}

// ---------------- launch ----------------
extern "C" void kernel_launch(void* const* d_in, const int* in_sizes, int n_in,
                              void* d_out, int out_size, void* d_ws, size_t ws_size,
                              hipStream_t stream) {
  const int* y_in = (const int*)d_in[0];
  const float* h0 = (const float*)d_in[1];
  const float* c0 = (const float*)d_in[2];
  const float* enc = (const float*)d_in[3];
  const int* mask = (const int*)d_in[4];
  const float* embed = (const float*)d_in[5];
  const float* W_ih0 = (const float*)d_in[6];
  const float* W_hh0 = (const float*)d_in[7];
  const float* b_ih0 = (const float*)d_in[8];
  const float* b_hh0 = (const float*)d_in[9];
  const float* W_ih1 = (const float*)d_in[10];
  const float* W_hh1 = (const float*)d_in[11];
  const float* b_ih1 = (const float*)d_in[12];
  const float* b_hh1 = (const float*)d_in[13];
  const float* fc_W = (const float*)d_in[14];
  const float* fc_b = (const float*)d_in[15];
  const float* out_W = (const float*)d_in[16];
  const float* out_b = (const float*)d_in[17];
  float* out = (float*)d_out;

  float* ws = (float*)d_ws;
  float* emb   = ws;                    // 2048*512          = 1,048,576
  float* xg    = emb + 1048576;         // 2048*4096         = 8,388,608
  float* hs0   = xg + 8388608;          // 2048*1024         = 2,097,152
  float* hs1   = hs0 + 2097152;         // 2048*1024         = 2,097,152
  float* hglob0 = hs1 + 2097152;        // 16*1024           = 16,384
  float* hglob1 = hglob0 + 16384;       // 16*1024           = 16,384
  unsigned* bar = (unsigned*)(hglob1 + 16384);
  float* cat = xg;                      // reuse xg region after LSTM1 (16 MB)
  float* h_t = xg + 4194304;            // next 8 MB of xg region

  hipMemsetAsync(bar, 0, 2 * sizeof(unsigned), stream);
  embed_kernel<<<1024, 256, 0, stream>>>(y_in, embed, emb);
  // xg0 = emb @ W_ih0^T + b_ih0 + b_hh0
  gemm_mfma<<<dim3(32, 16), 256, 0, stream>>>(emb, W_ih0, b_ih0, b_hh0, xg, 2048, 4096, 512, 0);
  lstm_kernel<<<256, 256, 0, stream>>>(xg, W_hh0, h0, c0, hglob0, hglob1, hs0, bar);
  // xg1 = hs0 @ W_ih1^T + b_ih1 + b_hh1
  gemm_mfma<<<dim3(32, 16), 256, 0, stream>>>(hs0, W_ih1, b_ih1, b_hh1, xg, 2048, 4096, 1024, 0);
  lstm_kernel<<<256, 256, 0, stream>>>(xg, W_hh1, h0 + 16384, c0 + 16384, hglob0, hglob1, hs1, bar);
  attn_kernel<<<2048, 256, 0, stream>>>(hs1, enc, mask, cat);
  // h_t = tanh(cat @ fc_W^T + fc_b)
  gemm_mfma<<<dim3(8, 16), 256, 0, stream>>>(cat, fc_W, fc_b, nullptr, h_t, 2048, 1024, 2048, 1);
  // logits = h_t @ out_W^T + out_b
  gemm_mfma<<<dim3(250, 16), 256, 0, stream>>>(h_t, out_W, out_b, nullptr, out, 2048, 32000, 1024, 0);
}

// Round 2
// 5911.621 us; speedup vs baseline: 2.8958x; 2.8958x over previous
//
#include <hip/hip_runtime.h>
#include <cstdint>
#include <cstddef>

#define TT 128   // T
#define NBATCH 16
#define HH 1024
#define G4 4096  // 4*H

typedef __attribute__((ext_vector_type(8))) short bf16x8;
typedef __attribute__((ext_vector_type(4))) float f32x4;

// ---------------- embedding gather ----------------
__global__ __launch_bounds__(256) void embed_kernel(const int* __restrict__ y,
    const float* __restrict__ embed, float* __restrict__ emb) {
  int idx = blockIdx.x * 256 + threadIdx.x;   // float4 index over [2048][128]
  int n = idx >> 7, c = idx & 127;
  int tok = y[n];
  reinterpret_cast<float4*>(emb)[idx] =
      reinterpret_cast<const float4*>(embed)[(size_t)tok * 128 + c];
}

// ---------------- split-bf16 helpers (truncation split: x = hi + lo + O(2^-14 x)) ----
__device__ __forceinline__ unsigned pkhi(float x, float y) {
  return (__float_as_uint(x) >> 16) | (__float_as_uint(y) & 0xFFFF0000u);
}
__device__ __forceinline__ float bfres(float x) {
  return x - __uint_as_float(__float_as_uint(x) & 0xFFFF0000u);
}

// ---------------- MFMA GEMM: C[M,N] = A[M,K]*W[N,K]^T + b1 (+b2), opt tanh --------
__global__ __launch_bounds__(256, 2) void gemm_mfma(
    const float* __restrict__ A, const float* __restrict__ W,
    const float* __restrict__ b1, const float* __restrict__ b2,
    float* __restrict__ C, int M, int N, int K, int act) {
  __shared__ short Ah[128][40];
  __shared__ short Al[128][40];
  __shared__ short Wh[128][40];
  __shared__ short Wl[128][40];

  const int tid = threadIdx.x;
  const int m0 = blockIdx.y * 128, n0 = blockIdx.x * 128;
  const int sr = tid >> 1;          // staging row 0..127
  const int kh = tid & 1;           // staging k-half (16 floats each)
  const int lane = tid & 63;
  const int wv = tid >> 6;          // wave 0..3
  const int wr = wv >> 1, wc = wv & 1;
  const int lr = lane & 15;         // frag row/col
  const int kg = lane >> 4;         // k-group 0..3 (8 elems each)

  const float* Ap = A + (size_t)(m0 + sr) * K + kh * 16;
  const float* Wp = W + (size_t)(n0 + sr) * K + kh * 16;

  f32x4 zero = {0.f, 0.f, 0.f, 0.f};
  f32x4 acc[4][4];
#pragma unroll
  for (int m = 0; m < 4; ++m)
#pragma unroll
    for (int n = 0; n < 4; ++n) acc[m][n] = zero;

  float4 qa[4], qw[4];
#pragma unroll
  for (int i = 0; i < 4; ++i) {
    qa[i] = *reinterpret_cast<const float4*>(Ap + i * 4);
    qw[i] = *reinterpret_cast<const float4*>(Wp + i * 4);
  }

  for (int k0 = 0; k0 < K; k0 += 32) {
    {
      unsigned ha[8], la[8], hw[8], lw[8];
#pragma unroll
      for (int i = 0; i < 4; ++i) {
        ha[2 * i]     = pkhi(qa[i].x, qa[i].y);
        ha[2 * i + 1] = pkhi(qa[i].z, qa[i].w);
        la[2 * i]     = pkhi(bfres(qa[i].x), bfres(qa[i].y));
        la[2 * i + 1] = pkhi(bfres(qa[i].z), bfres(qa[i].w));
        hw[2 * i]     = pkhi(qw[i].x, qw[i].y);
        hw[2 * i + 1] = pkhi(qw[i].z, qw[i].w);
        lw[2 * i]     = pkhi(bfres(qw[i].x), bfres(qw[i].y));
        lw[2 * i + 1] = pkhi(bfres(qw[i].z), bfres(qw[i].w));
      }
      *reinterpret_cast<uint4*>(&Ah[sr][kh * 16])     = make_uint4(ha[0], ha[1], ha[2], ha[3]);
      *reinterpret_cast<uint4*>(&Ah[sr][kh * 16 + 8]) = make_uint4(ha[4], ha[5], ha[6], ha[7]);
      *reinterpret_cast<uint4*>(&Al[sr][kh * 16])     = make_uint4(la[0], la[1], la[2], la[3]);
      *reinterpret_cast<uint4*>(&Al[sr][kh * 16 + 8]) = make_uint4(la[4], la[5], la[6], la[7]);
      *reinterpret_cast<uint4*>(&Wh[sr][kh * 16])     = make_uint4(hw[0], hw[1], hw[2], hw[3]);
      *reinterpret_cast<uint4*>(&Wh[sr][kh * 16 + 8]) = make_uint4(hw[4], hw[5], hw[6], hw[7]);
      *reinterpret_cast<uint4*>(&Wl[sr][kh * 16])     = make_uint4(lw[0], lw[1], lw[2], lw[3]);
      *reinterpret_cast<uint4*>(&Wl[sr][kh * 16 + 8]) = make_uint4(lw[4], lw[5], lw[6], lw[7]);
    }
    __syncthreads();

    if (k0 + 32 < K) {
#pragma unroll
      for (int i = 0; i < 4; ++i) {
        qa[i] = *reinterpret_cast<const float4*>(Ap + k0 + 32 + i * 4);
        qw[i] = *reinterpret_cast<const float4*>(Wp + k0 + 32 + i * 4);
      }
    }

    bf16x8 fah[4], fal[4], fbh[4], fbl[4];
#pragma unroll
    for (int m = 0; m < 4; ++m) {
      fah[m] = *reinterpret_cast<const bf16x8*>(&Ah[wr * 64 + m * 16 + lr][kg * 8]);
      fal[m] = *reinterpret_cast<const bf16x8*>(&Al[wr * 64 + m * 16 + lr][kg * 8]);
      fbh[m] = *reinterpret_cast<const bf16x8*>(&Wh[wc * 64 + m * 16 + lr][kg * 8]);
      fbl[m] = *reinterpret_cast<const bf16x8*>(&Wl[wc * 64 + m * 16 + lr][kg * 8]);
    }

#pragma unroll
    for (int m = 0; m < 4; ++m)
#pragma unroll
      for (int n = 0; n < 4; ++n)
        acc[m][n] = __builtin_amdgcn_mfma_f32_16x16x32_bf16(fah[m], fbh[n], acc[m][n], 0, 0, 0);
#pragma unroll
    for (int m = 0; m < 4; ++m)
#pragma unroll
      for (int n = 0; n < 4; ++n)
        acc[m][n] = __builtin_amdgcn_mfma_f32_16x16x32_bf16(fah[m], fbl[n], acc[m][n], 0, 0, 0);
#pragma unroll
    for (int m = 0; m < 4; ++m)
#pragma unroll
      for (int n = 0; n < 4; ++n)
        acc[m][n] = __builtin_amdgcn_mfma_f32_16x16x32_bf16(fal[m], fbh[n], acc[m][n], 0, 0, 0);
    __syncthreads();
  }

#pragma unroll
  for (int m = 0; m < 4; ++m) {
    int grow = m0 + wr * 64 + m * 16 + kg * 4;
#pragma unroll
    for (int n = 0; n < 4; ++n) {
      int gcol = n0 + wc * 64 + n * 16 + lr;
      float bias = b1[gcol] + (b2 ? b2[gcol] : 0.f);
#pragma unroll
      for (int rr = 0; rr < 4; ++rr) {
        float v = acc[m][n][rr] + bias;
        if (act) v = tanhf(v);
        C[(size_t)(grow + rr) * N + gcol] = v;
      }
    }
  }
}

// ---------------- grid barrier: two-level tree, relaxed spin -------------------
// bar layout (uint index, 128B-spaced lines): [0]=root, [32]=generation,
// [64 + g*32]=leaf counter for group g (16 groups of 16 blocks).
// Arrival: leaf acq_rel add -> (last of 16) root acq_rel add -> (last of 16 groups)
// gen release add. Spin on gen with RELAXED agent loads (sc1: reads through to IC,
// NO per-poll L2 invalidate, unlike an acquire load). One acquire load on exit
// orders the subsequent hbuf reads. Resets happen before the release flip, so they
// are visible to next-barrier arrivers via the acquire.
__device__ __forceinline__ void grid_barrier(unsigned* bar) {
  __syncthreads();
  if (threadIdx.x == 0) {
    unsigned* gen  = bar + 32;
    unsigned* leaf = bar + 64 + (blockIdx.x >> 4) * 32;
    unsigned g = __hip_atomic_load(gen, __ATOMIC_RELAXED, __HIP_MEMORY_SCOPE_AGENT);
    unsigned a = __hip_atomic_fetch_add(leaf, 1u, __ATOMIC_ACQ_REL, __HIP_MEMORY_SCOPE_AGENT);
    if (a == 15u) {                 // last of the 16 blocks in this group
      __hip_atomic_store(leaf, 0u, __ATOMIC_RELAXED, __HIP_MEMORY_SCOPE_AGENT);
      unsigned r = __hip_atomic_fetch_add(bar, 1u, __ATOMIC_ACQ_REL, __HIP_MEMORY_SCOPE_AGENT);
      if (r == 15u) {               // last of the 16 groups
        __hip_atomic_store(bar, 0u, __ATOMIC_RELAXED, __HIP_MEMORY_SCOPE_AGENT);
        __hip_atomic_fetch_add(gen, 1u, __ATOMIC_RELEASE, __HIP_MEMORY_SCOPE_AGENT);
      }
    }
    while (__hip_atomic_load(gen, __ATOMIC_RELAXED, __HIP_MEMORY_SCOPE_AGENT) == g) {
      __builtin_amdgcn_s_sleep(2);
    }
    (void)__hip_atomic_load(gen, __ATOMIC_ACQUIRE, __HIP_MEMORY_SCOPE_AGENT);
  }
  __syncthreads();
}

// ---------------- LSTM layer: persistent, 256 blocks, W_hh in registers ----------
__global__ __launch_bounds__(256) void lstm_kernel(
    const float* __restrict__ xg,    // [B*T, 4H], includes b_ih + b_hh
    const float* __restrict__ W_hh,  // [4H, H]
    const float* __restrict__ h0,    // [B,H] (layer slice)
    const float* __restrict__ c0,    // [B,H]
    float* __restrict__ hbuf0,       // [B,H] state buffer (even steps read)
    float* __restrict__ hbuf1,       // [B,H] state buffer (odd steps read)
    float* __restrict__ hs,          // [B*T, H] layer output
    unsigned* __restrict__ bar) {
  __shared__ float4 lds_h[16 * 256];                       // 64 KB: h[b][256 f4]
  float* lds_g = reinterpret_cast<float*>(lds_h);          // aliased gates [16][17]

  const int tid = threadIdx.x;
  const int bid = blockIdx.x;
  const int r = tid >> 4;          // 0..15
  const int ks = tid & 15;         // 0..15
  const int gate = r >> 2, jj = r & 3;
  const int grow = gate * HH + bid * 4 + jj;   // row in W_hh / column in xg

  // persistent W_hh fragment: 64 floats, k = ks*4 + 64*m + e
  float4 wreg[16];
#pragma unroll
  for (int m = 0; m < 16; ++m)
    wreg[m] = *reinterpret_cast<const float4*>(W_hh + (size_t)grow * HH + ks * 4 + 64 * m);

  // init c (held by consumer threads) and our slice of the step-0 read buffer
  float c_reg = 0.f;
  if (tid < 64) {
    int b = tid & 15, jl = tid >> 4;
    int j = bid * 4 + jl;
    c_reg = c0[b * HH + j];
    hbuf0[b * HH + j] = h0[b * HH + j];
  }
  grid_barrier(bar);

  float* cur = hbuf0;
  float* nxt = hbuf1;
  for (int t = 0; t < TT; ++t) {
    // prefetch this thread's xg value (b = ks)
    float xgv = xg[(size_t)(ks * TT + t) * G4 + grow];
    // stage h -> LDS (read buffer)
    const float4* hg4 = reinterpret_cast<const float4*>(cur);
#pragma unroll
    for (int i = 0; i < 16; ++i) {
      int idx = i * 256 + tid;         // 0..4095
      lds_h[idx] = hg4[idx];
    }
    __syncthreads();
    // partial dots for all 16 batches over this thread's K slice
    float acc[16];
#pragma unroll
    for (int b = 0; b < 16; ++b) {
      float fa = 0.f;
#pragma unroll
      for (int m = 0; m < 16; ++m) {
        float4 hv = lds_h[b * 256 + m * 16 + ks];
        fa += wreg[m].x * hv.x + wreg[m].y * hv.y + wreg[m].z * hv.z + wreg[m].w * hv.w;
      }
      acc[b] = fa;
    }
    // butterfly reduce across the 16 ks lanes (lane = (r&3)*16 + ks; masks flip ks only)
#pragma unroll
    for (int b = 0; b < 16; ++b) {
      float v = acc[b];
      v += __shfl_xor(v, 1);
      v += __shfl_xor(v, 2);
      v += __shfl_xor(v, 4);
      v += __shfl_xor(v, 8);
      acc[b] = v;
    }
    // this thread publishes gate value for b == ks
    float gv = acc[0];
#pragma unroll
    for (int b = 1; b < 16; ++b) if (ks == b) gv = acc[b];
    gv += xgv;
    __syncthreads();                // all lds_h reads done before aliasing as lds_g
    lds_g[r * 17 + ks] = gv;
    __syncthreads();
    if (tid < 64) {
      int b = tid & 15, jl = tid >> 4;
      float gi = lds_g[(0 * 4 + jl) * 17 + b];
      float gf = lds_g[(1 * 4 + jl) * 17 + b];
      float gg = lds_g[(2 * 4 + jl) * 17 + b];
      float go = lds_g[(3 * 4 + jl) * 17 + b];
      float si = 1.f / (1.f + expf(-gi));
      float sf = 1.f / (1.f + expf(-gf));
      float so = 1.f / (1.f + expf(-go));
      c_reg = sf * c_reg + si * tanhf(gg);
      float hv = so * tanhf(c_reg);
      int j = bid * 4 + jl;
      nxt[b * HH + j] = hv;                      // write buffer (no race with readers of cur)
      hs[(size_t)(b * TT + t) * HH + j] = hv;
    }
    grid_barrier(bar);
    float* tmp = cur; cur = nxt; nxt = tmp;
  }
}

// ---------------- attention + concat: per (b,t) block ----------------
__global__ __launch_bounds__(256) void attn_kernel(
    const float* __restrict__ hs1, const float* __restrict__ enc,
    const int* __restrict__ mask, float* __restrict__ cat) {
  __shared__ float4 q4[256];
  __shared__ float sc[128];
  __shared__ float red[8];
  const int tid = threadIdx.x;
  const int n = blockIdx.x;          // b*T + t
  const int b = n >> 7;

  float4 qv = reinterpret_cast<const float4*>(hs1)[(size_t)n * 256 + tid];
  q4[tid] = qv;
  reinterpret_cast<float4*>(cat)[(size_t)n * 512 + tid] = qv;   // cat first half
  __syncthreads();

  // scores: 2 threads per s (k-split halves)
  const int s = tid >> 1, half = tid & 1;
  const float4* e4 = reinterpret_cast<const float4*>(enc) + ((size_t)(b * 128 + s)) * 256 + half * 128;
  const float4* qq = q4 + half * 128;
  float p = 0.f;
#pragma unroll 8
  for (int k = 0; k < 128; ++k) {
    float4 ev = e4[k]; float4 qk = qq[k];
    p += ev.x * qk.x + ev.y * qk.y + ev.z * qk.z + ev.w * qk.w;
  }
  p += __shfl_xor(p, 1);
  if (half == 0) sc[s] = (mask[b * 128 + s] != 0) ? p : -1.0e9f;
  __syncthreads();

  // softmax over 128 scores
  const int lane = tid & 63;
  float v = (tid < 128) ? sc[tid] : -3.4e38f;
#pragma unroll
  for (int off = 32; off; off >>= 1) v = fmaxf(v, __shfl_xor(v, off));
  if (tid < 128 && lane == 0) red[tid >> 6] = v;
  __syncthreads();
  float mx = fmaxf(red[0], red[1]);
  float e = (tid < 128) ? expf(sc[tid] - mx) : 0.f;
  float sum = e;
#pragma unroll
  for (int off = 32; off; off >>= 1) sum += __shfl_xor(sum, off);
  if (lane == 0) red[4 + (tid >> 6)] = sum;
  __syncthreads();
  float tot = red[4] + red[5] + red[6] + red[7];
  if (tid < 128) sc[tid] = e / tot;
  __syncthreads();

  // ctx: each thread owns 4 h channels
  float4 accv = {0.f, 0.f, 0.f, 0.f};
  const float4* eb = reinterpret_cast<const float4*>(enc) + (size_t)b * 128 * 256;
#pragma unroll 4
  for (int ss = 0; ss < 128; ++ss) {
    float a = sc[ss];
    float4 ev = eb[(size_t)ss * 256 + tid];
    accv.x += a * ev.x; accv.y += a * ev.y; accv.z += a * ev.z; accv.w += a * ev.w;
  }
  reinterpret_cast<float4*>(cat)[(size_t)n * 512 + 256 + tid] = accv;
}

// ---------------- launch ----------------
extern "C" void kernel_launch(void* const* d_in, const int* in_sizes, int n_in,
                              void* d_out, int out_size, void* d_ws, size_t ws_size,
                              hipStream_t stream) {
  const int* y_in = (const int*)d_in[0];
  const float* h0 = (const float*)d_in[1];
  const float* c0 = (const float*)d_in[2];
  const float* enc = (const float*)d_in[3];
  const int* mask = (const int*)d_in[4];
  const float* embed = (const float*)d_in[5];
  const float* W_ih0 = (const float*)d_in[6];
  const float* W_hh0 = (const float*)d_in[7];
  const float* b_ih0 = (const float*)d_in[8];
  const float* b_hh0 = (const float*)d_in[9];
  const float* W_ih1 = (const float*)d_in[10];
  const float* W_hh1 = (const float*)d_in[11];
  const float* b_ih1 = (const float*)d_in[12];
  const float* b_hh1 = (const float*)d_in[13];
  const float* fc_W = (const float*)d_in[14];
  const float* fc_b = (const float*)d_in[15];
  const float* out_W = (const float*)d_in[16];
  const float* out_b = (const float*)d_in[17];
  float* out = (float*)d_out;

  float* ws = (float*)d_ws;
  float* emb   = ws;                    // 2048*512          = 1,048,576
  float* xg    = emb + 1048576;         // 2048*4096         = 8,388,608
  float* hs0   = xg + 8388608;          // 2048*1024         = 2,097,152
  float* hs1   = hs0 + 2097152;         // 2048*1024         = 2,097,152
  float* hglob0 = hs1 + 2097152;        // 16*1024           = 16,384
  float* hglob1 = hglob0 + 16384;       // 16*1024           = 16,384
  unsigned* bar = (unsigned*)(hglob1 + 16384);   // 1024 uints (two-level tree)
  float* cat = xg;                      // reuse xg region after LSTM1 (16 MB)
  float* h_t = xg + 4194304;            // next 8 MB of xg region

  hipMemsetAsync(bar, 0, 1024 * sizeof(unsigned), stream);
  embed_kernel<<<1024, 256, 0, stream>>>(y_in, embed, emb);
  // xg0 = emb @ W_ih0^T + b_ih0 + b_hh0
  gemm_mfma<<<dim3(32, 16), 256, 0, stream>>>(emb, W_ih0, b_ih0, b_hh0, xg, 2048, 4096, 512, 0);
  lstm_kernel<<<256, 256, 0, stream>>>(xg, W_hh0, h0, c0, hglob0, hglob1, hs0, bar);
  // xg1 = hs0 @ W_ih1^T + b_ih1 + b_hh1
  gemm_mfma<<<dim3(32, 16), 256, 0, stream>>>(hs0, W_ih1, b_ih1, b_hh1, xg, 2048, 4096, 1024, 0);
  lstm_kernel<<<256, 256, 0, stream>>>(xg, W_hh1, h0 + 16384, c0 + 16384, hglob0, hglob1, hs1, bar);
  attn_kernel<<<2048, 256, 0, stream>>>(hs1, enc, mask, cat);
  // h_t = tanh(cat @ fc_W^T + fc_b)
  gemm_mfma<<<dim3(8, 16), 256, 0, stream>>>(cat, fc_W, fc_b, nullptr, h_t, 2048, 1024, 2048, 1);
  // logits = h_t @ out_W^T + out_b
  gemm_mfma<<<dim3(250, 16), 256, 0, stream>>>(h_t, out_W, out_b, nullptr, out, 2048, 32000, 1024, 0);
}